// Round 1
// baseline (181.206 us; speedup 1.0000x reference)
//
#include <hip/hip_runtime.h>

#define EPS 1e-5f

typedef __attribute__((ext_vector_type(8))) __bf16 bf16x8;
typedef __attribute__((ext_vector_type(4))) float f32x4;

__device__ __forceinline__ void async_copy16(const void* g, void* l) {
  __builtin_amdgcn_global_load_lds(
      (const __attribute__((address_space(1))) unsigned int*)g,
      (__attribute__((address_space(3))) unsigned int*)l, 16, 0, 0);
}

__device__ __forceinline__ float silu_f(float v) {
  return v / (1.f + __expf(-v));
}

// ---------------- prep: fold BN + scales ----------------
// block 0: per-channel expert fold (eff_kernel[256][9], eff_bias[256], bias2[256])
// blocks 1..256: w_eff[o][c] = w_out[o][c] * t2[o]  (bf16)
__global__ __launch_bounds__(256) void prep_kernel(
    const float* __restrict__ w_experts, const float* __restrict__ bn_gamma,
    const float* __restrict__ bn_beta, const float* __restrict__ bn_mean,
    const float* __restrict__ bn_var, const float* __restrict__ scales,
    const float* __restrict__ w_out, const float* __restrict__ out_gamma,
    const float* __restrict__ out_beta, const float* __restrict__ out_mean,
    const float* __restrict__ out_var,
    float* __restrict__ eff_kernel, float* __restrict__ eff_bias,
    __bf16* __restrict__ w_eff, float* __restrict__ bias2)
{
  const int t = threadIdx.x;
  if (blockIdx.x == 0) {
    const int c = t;
    float k9[9];
#pragma unroll
    for (int r = 0; r < 9; ++r) k9[r] = 0.f;
    float bias = 0.f;
    for (int e = 0; e < 9; ++e) {
      const int ec = e * 256 + c;
      const float tt = bn_gamma[ec] * rsqrtf(bn_var[ec] + EPS);
      const float sc = scales[ec];
      const float es = tt * sc;
      bias += (bn_beta[ec] - bn_mean[ec] * tt) * sc;
      const float* wp = w_experts + (size_t)ec * 9;
#pragma unroll
      for (int r = 0; r < 9; ++r) k9[r] += es * wp[r];
    }
#pragma unroll
    for (int r = 0; r < 9; ++r) eff_kernel[c * 9 + r] = k9[r];
    eff_bias[c] = bias;
    const float t2 = out_gamma[c] * rsqrtf(out_var[c] + EPS);
    bias2[c] = out_beta[c] - out_mean[c] * t2;
  } else {
    const int i = (blockIdx.x - 1) * 256 + t;   // 0..65535
    const int o = i >> 8;
    const float t2 = out_gamma[o] * rsqrtf(out_var[o] + EPS);
    w_eff[i] = (__bf16)(w_out[i] * t2);
  }
}

// ---------------- depthwise 3x3 + bias + SiLU, NCHW fp32 -> NHWC bf16 -------
// grid: 512 blocks = (b,h); 256 threads: wave = one image row at one channel.
__global__ __launch_bounds__(256) void dw_kernel(
    const float* __restrict__ x, const float* __restrict__ eff_kernel,
    const float* __restrict__ eff_bias, __bf16* __restrict__ moe)
{
  __shared__ __align__(16) __bf16 lds_t[64 * 264];  // [w][c], pad 264 for banks+align
  __shared__ float kern_s[256 * 9];
  __shared__ float bias_s[256];
  const int t = threadIdx.x;
  const int b = blockIdx.x >> 6;
  const int h = blockIdx.x & 63;
  for (int i = t; i < 256 * 9; i += 256) kern_s[i] = eff_kernel[i];
  bias_s[t] = eff_bias[t];
  __syncthreads();

  const int w = t & 63;       // lane == w: wave covers one full row
  const int cbase = t >> 6;   // wave id 0..3
  for (int cc = 0; cc < 64; ++cc) {
    const int c = cc * 4 + cbase;
    const float* kp = &kern_s[c * 9];
    float s = bias_s[c];
    const float* xc = x + (size_t)(b * 256 + c) * 4096;
#pragma unroll
    for (int dh = -1; dh <= 1; ++dh) {
      const int hh = h + dh;                 // wave-uniform condition
      if ((unsigned)hh < 64u) {
        const float v = xc[hh * 64 + w];     // coalesced 256B per wave
        float vl = __shfl_up(v, 1);
        float vr = __shfl_down(v, 1);
        if (w == 0) vl = 0.f;                // SAME zero padding
        if (w == 63) vr = 0.f;
        const float* kr = kp + (dh + 1) * 3;
        s += vl * kr[0] + v * kr[1] + vr * kr[2];
      }
    }
    lds_t[w * 264 + c] = (__bf16)silu_f(s);
  }
  __syncthreads();

  // transpose-out: 16B/lane stores, 512B contiguous per pixel
  const int pix0 = (b * 64 + h) * 64;
  const int w2b = t >> 5;
  const int c8 = (t & 31) * 8;
  for (int it = 0; it < 8; ++it) {
    const int w2 = it * 8 + w2b;
    const uint4 v = *(const uint4*)&lds_t[w2 * 264 + c8];
    *(uint4*)&moe[(size_t)(pix0 + w2) * 256 + c8] = v;
  }
}

// ---------------- GEMM: out[o,p] = silu(bias2[o] + sum_c w_eff[o,c]*moe[p,c])
// A = w_eff [256][256] bf16 (K-contig), B = moe NHWC [32768][256] bf16 (K-contig)
// tile 128(o) x 128(p), BK=64, 4 waves each 64x64 via 4x4 frags of 16x16x32.
__global__ __launch_bounds__(256) void gemm_kernel(
    const __bf16* __restrict__ moe, const __bf16* __restrict__ w_eff,
    const float* __restrict__ bias2, float* __restrict__ out)
{
  __shared__ __align__(16) __bf16 A_lds[128 * 64];
  __shared__ __align__(16) __bf16 B_lds[128 * 64];
  const int t = threadIdx.x;
  const int lane = t & 63;
  const int wv = t >> 6;
  const int o0 = (blockIdx.x & 1) * 128;
  const int P0 = (blockIdx.x >> 1) * 128;    // global pixel; 4096%128==0 -> one batch
  const int quad = lane >> 4, l15 = lane & 15;
  const int wave_o = (wv >> 1) * 64, wave_p = (wv & 1) * 64;

  f32x4 acc[4][4];
#pragma unroll
  for (int i = 0; i < 4; ++i)
#pragma unroll
    for (int j = 0; j < 4; ++j) acc[i][j] = (f32x4){0.f, 0.f, 0.f, 0.f};

  const char* gA0 = (const char*)w_eff + (size_t)o0 * 512;
  const char* gB0 = (const char*)moe + (size_t)P0 * 512;

  for (int kt = 0; kt < 4; ++kt) {
#pragma unroll
    for (int i = 0; i < 4; ++i) {
      const int lin = i * 4096 + t * 16;     // byte within 16KB tile
      const int r = lin >> 7;                // tile row
      const int kb = lin & 127;              // byte within 128B row-segment
      async_copy16(gA0 + (size_t)r * 512 + kt * 128 + kb, (char*)A_lds + lin);
      async_copy16(gB0 + (size_t)r * 512 + kt * 128 + kb, (char*)B_lds + lin);
    }
    __syncthreads();
#pragma unroll
    for (int kk = 0; kk < 2; ++kk) {
      bf16x8 af[4], bf[4];
#pragma unroll
      for (int i = 0; i < 4; ++i)
        af[i] = *(const bf16x8*)&A_lds[(wave_o + i * 16 + l15) * 64 + kk * 32 + quad * 8];
#pragma unroll
      for (int j = 0; j < 4; ++j)
        bf[j] = *(const bf16x8*)&B_lds[(wave_p + j * 16 + l15) * 64 + kk * 32 + quad * 8];
#pragma unroll
      for (int i = 0; i < 4; ++i)
#pragma unroll
        for (int j = 0; j < 4; ++j)
          acc[i][j] = __builtin_amdgcn_mfma_f32_16x16x32_bf16(af[i], bf[j], acc[i][j], 0, 0, 0);
    }
    __syncthreads();
  }

  // epilogue: bias + SiLU, fp32 NCHW stores (lanes -> consecutive pixels)
  const int b = P0 >> 12;
  const int p_in_b = P0 & 4095;
  float* outb = out + (size_t)b * 256 * 4096;
#pragma unroll
  for (int i = 0; i < 4; ++i) {
#pragma unroll
    for (int r = 0; r < 4; ++r) {
      const int o = o0 + wave_o + i * 16 + quad * 4 + r;
      const float bo = bias2[o];
#pragma unroll
      for (int j = 0; j < 4; ++j) {
        const int p = p_in_b + wave_p + j * 16 + l15;
        outb[(size_t)o * 4096 + p] = silu_f(acc[i][j][r] + bo);
      }
    }
  }
}

extern "C" void kernel_launch(void* const* d_in, const int* in_sizes, int n_in,
                              void* d_out, int out_size, void* d_ws, size_t ws_size,
                              hipStream_t stream) {
  const float* x         = (const float*)d_in[0];
  const float* w_experts = (const float*)d_in[1];
  const float* bn_gamma  = (const float*)d_in[2];
  const float* bn_beta   = (const float*)d_in[3];
  const float* bn_mean   = (const float*)d_in[4];
  const float* bn_var    = (const float*)d_in[5];
  const float* scales    = (const float*)d_in[6];
  const float* w_out     = (const float*)d_in[7];
  const float* out_gamma = (const float*)d_in[8];
  const float* out_beta  = (const float*)d_in[9];
  const float* out_mean  = (const float*)d_in[10];
  const float* out_var   = (const float*)d_in[11];
  float* out = (float*)d_out;

  char* ws = (char*)d_ws;
  __bf16* moe       = (__bf16*)(ws);                 // 16 MiB: [32768][256] bf16 NHWC
  float* eff_kernel = (float*)(ws + 16777216);       // 9216 B
  float* eff_bias   = (float*)(ws + 16786432);       // 1 KiB
  __bf16* w_eff     = (__bf16*)(ws + 16787456);      // 128 KiB
  float* bias2      = (float*)(ws + 16918528);       // 1 KiB

  hipLaunchKernelGGL(prep_kernel, dim3(257), dim3(256), 0, stream,
                     w_experts, bn_gamma, bn_beta, bn_mean, bn_var, scales,
                     w_out, out_gamma, out_beta, out_mean, out_var,
                     eff_kernel, eff_bias, w_eff, bias2);
  hipLaunchKernelGGL(dw_kernel, dim3(512), dim3(256), 0, stream,
                     x, eff_kernel, eff_bias, moe);
  hipLaunchKernelGGL(gemm_kernel, dim3(512), dim3(256), 0, stream,
                     moe, w_eff, bias2, out);
}

// Round 2
// 128.078 us; speedup vs baseline: 1.4148x; 1.4148x over previous
//
#include <hip/hip_runtime.h>

#define EPS 1e-5f

typedef __attribute__((ext_vector_type(8))) __bf16 bf16x8;
typedef __attribute__((ext_vector_type(4))) float f32x4;

__device__ __forceinline__ void async_copy16(const void* g, void* l) {
  __builtin_amdgcn_global_load_lds(
      (const __attribute__((address_space(1))) unsigned int*)g,
      (__attribute__((address_space(3))) unsigned int*)l, 16, 0, 0);
}

__device__ __forceinline__ float silu_f(float v) {
  return v / (1.f + __expf(-v));
}

// ---------------- prep: fold BN + scales ----------------
__global__ __launch_bounds__(256) void prep_kernel(
    const float* __restrict__ w_experts, const float* __restrict__ bn_gamma,
    const float* __restrict__ bn_beta, const float* __restrict__ bn_mean,
    const float* __restrict__ bn_var, const float* __restrict__ scales,
    const float* __restrict__ w_out, const float* __restrict__ out_gamma,
    const float* __restrict__ out_beta, const float* __restrict__ out_mean,
    const float* __restrict__ out_var,
    float* __restrict__ eff_kernel, float* __restrict__ eff_bias,
    __bf16* __restrict__ w_eff, float* __restrict__ bias2)
{
  const int t = threadIdx.x;
  if (blockIdx.x == 0) {
    const int c = t;
    float k9[9];
#pragma unroll
    for (int r = 0; r < 9; ++r) k9[r] = 0.f;
    float bias = 0.f;
    for (int e = 0; e < 9; ++e) {
      const int ec = e * 256 + c;
      const float tt = bn_gamma[ec] * rsqrtf(bn_var[ec] + EPS);
      const float sc = scales[ec];
      const float es = tt * sc;
      bias += (bn_beta[ec] - bn_mean[ec] * tt) * sc;
      const float* wp = w_experts + (size_t)ec * 9;
#pragma unroll
      for (int r = 0; r < 9; ++r) k9[r] += es * wp[r];
    }
#pragma unroll
    for (int r = 0; r < 9; ++r) eff_kernel[c * 9 + r] = k9[r];
    eff_bias[c] = bias;
    const float t2 = out_gamma[c] * rsqrtf(out_var[c] + EPS);
    bias2[c] = out_beta[c] - out_mean[c] * t2;
  } else {
    const int i = (blockIdx.x - 1) * 256 + t;   // 0..65535
    const int o = i >> 8;
    const float t2 = out_gamma[o] * rsqrtf(out_var[o] + EPS);
    w_eff[i] = (__bf16)(w_out[i] * t2);
  }
}

// ---------------- depthwise 3x3 + bias + SiLU, NCHW fp32 -> NHWC bf16 -------
// grid 2048 = (b, h, cg): cg = 64-channel quarter. 256 thr = 4 waves x 16 ch.
// Within a wave: 4 lane-groups of 16; lane-group lg handles one channel,
// lane covers 4 w positions via float4 (one load instr = 1KB = 4 rows).
__global__ __launch_bounds__(256) void dw_kernel(
    const float* __restrict__ x, const float* __restrict__ eff_kernel,
    const float* __restrict__ eff_bias, __bf16* __restrict__ moe)
{
  __shared__ __align__(16) __bf16 lds_t[64 * 72];  // [w][c_local], stride 72
  __shared__ float kern_s[64 * 9];
  __shared__ float bias_s[64];
  const int t = threadIdx.x;
  const int cg = blockIdx.x & 3;
  const int h = (blockIdx.x >> 2) & 63;
  const int b = blockIdx.x >> 8;

  if (t < 64) bias_s[t] = eff_bias[cg * 64 + t];
  for (int i = t; i < 576; i += 256) kern_s[i] = eff_kernel[cg * 576 + i];
  __syncthreads();

  const int lane = t & 63;
  const int wv = t >> 6;
  const int lg = lane >> 4;     // lane group -> channel
  const int wq = lane & 15;     // 16 lanes cover the 64-wide row (float4 each)
  const int w4 = wq * 4;
  const bool up_ok = (h > 0), dn_ok = (h < 63);

#pragma unroll
  for (int cc4 = 0; cc4 < 4; ++cc4) {
    const int ch = wv * 16 + cc4 * 4 + lg;          // 0..63 local channel
    const float* xc = x + ((size_t)(b * 256 + cg * 64 + ch) * 64) * 64;

    float4 v0, v1, v2;
    v1 = *(const float4*)(xc + h * 64 + w4);
    if (up_ok) v0 = *(const float4*)(xc + (h - 1) * 64 + w4);
    else       v0 = make_float4(0.f, 0.f, 0.f, 0.f);
    if (dn_ok) v2 = *(const float4*)(xc + (h + 1) * 64 + w4);
    else       v2 = make_float4(0.f, 0.f, 0.f, 0.f);

    float k[9];
#pragma unroll
    for (int j = 0; j < 9; ++j) k[j] = kern_s[ch * 9 + j];
    const float bias = bias_s[ch];

    float rowv[3][6];
    const float4 vv[3] = {v0, v1, v2};
#pragma unroll
    for (int r = 0; r < 3; ++r) {
      float vl = __shfl_up(vv[r].w, 1);
      float vr = __shfl_down(vv[r].x, 1);
      rowv[r][0] = (wq == 0) ? 0.f : vl;     // w4-1 (image-left edge at group start)
      rowv[r][1] = vv[r].x;
      rowv[r][2] = vv[r].y;
      rowv[r][3] = vv[r].z;
      rowv[r][4] = vv[r].w;
      rowv[r][5] = (wq == 15) ? 0.f : vr;    // w4+4
    }

#pragma unroll
    for (int j = 0; j < 4; ++j) {
      float s = bias;
#pragma unroll
      for (int r = 0; r < 3; ++r)
        s += k[r * 3] * rowv[r][j] + k[r * 3 + 1] * rowv[r][j + 1] + k[r * 3 + 2] * rowv[r][j + 2];
      lds_t[(w4 + j) * 72 + ch] = (__bf16)silu_f(s);
    }
  }
  __syncthreads();

  // transpose-out: 2 x 16B per lane; 128B contiguous per pixel segment
  const int pix0 = (b * 64 + h) * 64;
#pragma unroll
  for (int it = 0; it < 2; ++it) {
    const int idx = it * 256 + t;
    const int w2 = idx >> 3;
    const int c8 = (idx & 7) * 8;
    const uint4 v = *(const uint4*)&lds_t[w2 * 72 + c8];
    *(uint4*)&moe[(size_t)(pix0 + w2) * 256 + cg * 64 + c8] = v;
  }
}

// ---------------- GEMM: out[o,p] = silu(bias2[o] + sum_c w_eff[o,c]*moe[p,c])
// Tile 256(o) x 32(p), BK=64: 1024 blocks (4/CU), moe read exactly once.
// 4 waves, each 64(o) x 32(p) via 4x2 frags of 16x16x32.
__global__ __launch_bounds__(256) void gemm_kernel(
    const __bf16* __restrict__ moe, const __bf16* __restrict__ w_eff,
    const float* __restrict__ bias2, float* __restrict__ out)
{
  __shared__ __align__(16) __bf16 A_lds[256 * 64];   // 32 KB
  __shared__ __align__(16) __bf16 B_lds[32 * 64];    // 4 KB
  const int t = threadIdx.x;
  const int lane = t & 63;
  const int wv = t >> 6;
  const int P0 = blockIdx.x * 32;       // global pixel tile (4096 % 32 == 0)
  const int quad = lane >> 4, l15 = lane & 15;
  const int wave_o = wv * 64;

  f32x4 acc[4][2];
#pragma unroll
  for (int i = 0; i < 4; ++i)
#pragma unroll
    for (int j = 0; j < 2; ++j) acc[i][j] = (f32x4){0.f, 0.f, 0.f, 0.f};

  const char* gA0 = (const char*)w_eff;                    // [256][512B]
  const char* gB0 = (const char*)moe + (size_t)P0 * 512;   // [32][512B]

  for (int kt = 0; kt < 4; ++kt) {
    // A: 32KB = 8 x 16B per thread
#pragma unroll
    for (int i = 0; i < 8; ++i) {
      const int lin = i * 4096 + t * 16;
      const int r = lin >> 7;
      const int kb = lin & 127;
      async_copy16(gA0 + (size_t)r * 512 + kt * 128 + kb, (char*)A_lds + lin);
    }
    // B: 4KB = 1 x 16B per thread
    {
      const int r = t >> 3;
      const int kb = (t & 7) * 16;
      async_copy16(gB0 + (size_t)r * 512 + kt * 128 + kb, (char*)B_lds + t * 16);
    }
    __syncthreads();
#pragma unroll
    for (int kk = 0; kk < 2; ++kk) {
      bf16x8 af[4], bf[2];
#pragma unroll
      for (int i = 0; i < 4; ++i)
        af[i] = *(const bf16x8*)&A_lds[(wave_o + i * 16 + l15) * 64 + kk * 32 + quad * 8];
#pragma unroll
      for (int j = 0; j < 2; ++j)
        bf[j] = *(const bf16x8*)&B_lds[(j * 16 + l15) * 64 + kk * 32 + quad * 8];
#pragma unroll
      for (int i = 0; i < 4; ++i)
#pragma unroll
        for (int j = 0; j < 2; ++j)
          acc[i][j] = __builtin_amdgcn_mfma_f32_16x16x32_bf16(af[i], bf[j], acc[i][j], 0, 0, 0);
    }
    __syncthreads();
  }

  // epilogue: bias + SiLU, fp32 NCHW stores
  const int b = P0 >> 12;
  const int p_in_b = P0 & 4095;
  float* outb = out + (size_t)b * 256 * 4096;
#pragma unroll
  for (int i = 0; i < 4; ++i) {
#pragma unroll
    for (int r = 0; r < 4; ++r) {
      const int o = wave_o + i * 16 + quad * 4 + r;
      const float bo = bias2[o];
#pragma unroll
      for (int j = 0; j < 2; ++j) {
        const int p = p_in_b + j * 16 + l15;
        outb[(size_t)o * 4096 + p] = silu_f(acc[i][j][r] + bo);
      }
    }
  }
}

extern "C" void kernel_launch(void* const* d_in, const int* in_sizes, int n_in,
                              void* d_out, int out_size, void* d_ws, size_t ws_size,
                              hipStream_t stream) {
  const float* x         = (const float*)d_in[0];
  const float* w_experts = (const float*)d_in[1];
  const float* bn_gamma  = (const float*)d_in[2];
  const float* bn_beta   = (const float*)d_in[3];
  const float* bn_mean   = (const float*)d_in[4];
  const float* bn_var    = (const float*)d_in[5];
  const float* scales    = (const float*)d_in[6];
  const float* w_out     = (const float*)d_in[7];
  const float* out_gamma = (const float*)d_in[8];
  const float* out_beta  = (const float*)d_in[9];
  const float* out_mean  = (const float*)d_in[10];
  const float* out_var   = (const float*)d_in[11];
  float* out = (float*)d_out;

  char* ws = (char*)d_ws;
  __bf16* moe       = (__bf16*)(ws);                 // 16 MiB: [32768][256] bf16 NHWC
  float* eff_kernel = (float*)(ws + 16777216);       // 9216 B
  float* eff_bias   = (float*)(ws + 16786432);       // 1 KiB
  __bf16* w_eff     = (__bf16*)(ws + 16787456);      // 128 KiB
  float* bias2      = (float*)(ws + 16918528);       // 1 KiB

  hipLaunchKernelGGL(prep_kernel, dim3(257), dim3(256), 0, stream,
                     w_experts, bn_gamma, bn_beta, bn_mean, bn_var, scales,
                     w_out, out_gamma, out_beta, out_mean, out_var,
                     eff_kernel, eff_bias, w_eff, bias2);
  hipLaunchKernelGGL(dw_kernel, dim3(2048), dim3(256), 0, stream,
                     x, eff_kernel, eff_bias, moe);
  hipLaunchKernelGGL(gemm_kernel, dim3(1024), dim3(256), 0, stream,
                     moe, w_eff, bias2, out);
}

// Round 3
// 126.194 us; speedup vs baseline: 1.4359x; 1.0149x over previous
//
#include <hip/hip_runtime.h>

#define EPS 1e-5f

typedef __attribute__((ext_vector_type(8))) __bf16 bf16x8;
typedef __attribute__((ext_vector_type(4))) float f32x4;

__device__ __forceinline__ float silu_f(float v) {
  return v / (1.f + __expf(-v));
}

// ---------------- prep: fold BN + scales ----------------
__global__ __launch_bounds__(256) void prep_kernel(
    const float* __restrict__ w_experts, const float* __restrict__ bn_gamma,
    const float* __restrict__ bn_beta, const float* __restrict__ bn_mean,
    const float* __restrict__ bn_var, const float* __restrict__ scales,
    const float* __restrict__ w_out, const float* __restrict__ out_gamma,
    const float* __restrict__ out_beta, const float* __restrict__ out_mean,
    const float* __restrict__ out_var,
    float* __restrict__ eff_kernel, float* __restrict__ eff_bias,
    __bf16* __restrict__ w_eff, float* __restrict__ bias2)
{
  const int t = threadIdx.x;
  if (blockIdx.x == 0) {
    const int c = t;
    float k9[9];
#pragma unroll
    for (int r = 0; r < 9; ++r) k9[r] = 0.f;
    float bias = 0.f;
    for (int e = 0; e < 9; ++e) {
      const int ec = e * 256 + c;
      const float tt = bn_gamma[ec] * rsqrtf(bn_var[ec] + EPS);
      const float sc = scales[ec];
      const float es = tt * sc;
      bias += (bn_beta[ec] - bn_mean[ec] * tt) * sc;
      const float* wp = w_experts + (size_t)ec * 9;
#pragma unroll
      for (int r = 0; r < 9; ++r) k9[r] += es * wp[r];
    }
#pragma unroll
    for (int r = 0; r < 9; ++r) eff_kernel[c * 9 + r] = k9[r];
    eff_bias[c] = bias;
    const float t2 = out_gamma[c] * rsqrtf(out_var[c] + EPS);
    bias2[c] = out_beta[c] - out_mean[c] * t2;
  } else {
    const int i = (blockIdx.x - 1) * 256 + t;   // 0..65535
    const int o = i >> 8;
    const float t2 = out_gamma[o] * rsqrtf(out_var[o] + EPS);
    w_eff[i] = (__bf16)(w_out[i] * t2);
  }
}

// ---------------- fused: depthwise 3x3 + SiLU -> LDS -> MFMA out-proj -------
// One block per (b,h) image row. Phase 1: moe[64 px][256 ch] bf16 into LDS.
// Phase 2: out[o,p] = silu(bias2[o] + sum_c w_eff[o,c]*moe[p,c]); A (w_eff)
// loaded global->register fragments (L2-hot, no barrier in K-loop).
__global__ __launch_bounds__(256) void fused_kernel(
    const float* __restrict__ x, const float* __restrict__ eff_kernel,
    const float* __restrict__ eff_bias, const __bf16* __restrict__ w_eff,
    const float* __restrict__ bias2, float* __restrict__ out)
{
  __shared__ __align__(16) __bf16 B_lds[64 * 264];  // [pixel][ch], pad 264
  __shared__ float kern_s[256 * 9];
  __shared__ float bias_s[256];
  const int t = threadIdx.x;
  // XCD swizzle: blockIdx%8 -> h-group of 8 rows, so each XCD's L2 sees a
  // contiguous h-band (stencil rows re-read from same L2, all 8 batches).
  const int id = blockIdx.x;
  const int hg = id & 7;
  const int idx2 = id >> 3;          // 0..63
  const int b = idx2 & 7;
  const int h = hg * 8 + (idx2 >> 3);

  for (int i = t; i < 2304; i += 256) kern_s[i] = eff_kernel[i];
  bias_s[t] = eff_bias[t];
  __syncthreads();

  const int lane = t & 63;
  const int wv = t >> 6;
  const int lg = lane >> 4;     // lane group -> channel offset
  const int wq = lane & 15;     // 16 lanes cover the 64-wide row (float4 each)
  const int w4 = wq * 4;
  const bool up_ok = (h > 0), dn_ok = (h < 63);

  for (int cg = 0; cg < 4; ++cg) {
#pragma unroll
    for (int cc4 = 0; cc4 < 4; ++cc4) {
      const int ch = cg * 64 + wv * 16 + cc4 * 4 + lg;    // 0..255
      const float* xc = x + (size_t)(b * 256 + ch) * 4096;

      float4 v0, v1, v2;
      v1 = *(const float4*)(xc + h * 64 + w4);
      if (up_ok) v0 = *(const float4*)(xc + (h - 1) * 64 + w4);
      else       v0 = make_float4(0.f, 0.f, 0.f, 0.f);
      if (dn_ok) v2 = *(const float4*)(xc + (h + 1) * 64 + w4);
      else       v2 = make_float4(0.f, 0.f, 0.f, 0.f);

      float k[9];
#pragma unroll
      for (int j = 0; j < 9; ++j) k[j] = kern_s[ch * 9 + j];
      const float bias = bias_s[ch];

      float rowv[3][6];
      const float4 vv[3] = {v0, v1, v2};
#pragma unroll
      for (int r = 0; r < 3; ++r) {
        float vl = __shfl_up(vv[r].w, 1);
        float vr = __shfl_down(vv[r].x, 1);
        rowv[r][0] = (wq == 0) ? 0.f : vl;    // SAME left edge
        rowv[r][1] = vv[r].x;
        rowv[r][2] = vv[r].y;
        rowv[r][3] = vv[r].z;
        rowv[r][4] = vv[r].w;
        rowv[r][5] = (wq == 15) ? 0.f : vr;   // SAME right edge
      }

#pragma unroll
      for (int j = 0; j < 4; ++j) {
        float s = bias;
#pragma unroll
        for (int r = 0; r < 3; ++r)
          s += k[r * 3] * rowv[r][j] + k[r * 3 + 1] * rowv[r][j + 1] + k[r * 3 + 2] * rowv[r][j + 2];
        B_lds[(w4 + j) * 264 + ch] = (__bf16)silu_f(s);
      }
    }
  }
  __syncthreads();

  // ---- GEMM phase: M=256(o) x N=64(p) x K=256(c), 4 waves of 64(o) x 64(p)
  const int quad = lg;          // lane>>4
  const int l15 = wq;           // lane&15
  const int wave_o = wv * 64;

  f32x4 acc[4][4];
#pragma unroll
  for (int i = 0; i < 4; ++i)
#pragma unroll
    for (int j = 0; j < 4; ++j) acc[i][j] = (f32x4){0.f, 0.f, 0.f, 0.f};

#pragma unroll
  for (int kk = 0; kk < 8; ++kk) {            // 8 x K32, no barriers
    bf16x8 af[4], bf[4];
#pragma unroll
    for (int i = 0; i < 4; ++i)
      af[i] = *(const bf16x8*)&w_eff[(size_t)(wave_o + i * 16 + l15) * 256 + kk * 32 + quad * 8];
#pragma unroll
    for (int j = 0; j < 4; ++j)
      bf[j] = *(const bf16x8*)&B_lds[(j * 16 + l15) * 264 + kk * 32 + quad * 8];
#pragma unroll
    for (int i = 0; i < 4; ++i)
#pragma unroll
      for (int j = 0; j < 4; ++j)
        acc[i][j] = __builtin_amdgcn_mfma_f32_16x16x32_bf16(af[i], bf[j], acc[i][j], 0, 0, 0);
  }

  // epilogue: bias + SiLU, fp32 NCHW stores
  float* outb = out + (size_t)b * 256 * 4096 + h * 64;
#pragma unroll
  for (int i = 0; i < 4; ++i) {
#pragma unroll
    for (int r = 0; r < 4; ++r) {
      const int o = wave_o + i * 16 + quad * 4 + r;
      const float bo = bias2[o];
#pragma unroll
      for (int j = 0; j < 4; ++j) {
        const int p = j * 16 + l15;
        outb[(size_t)o * 4096 + p] = silu_f(acc[i][j][r] + bo);
      }
    }
  }
}

extern "C" void kernel_launch(void* const* d_in, const int* in_sizes, int n_in,
                              void* d_out, int out_size, void* d_ws, size_t ws_size,
                              hipStream_t stream) {
  const float* x         = (const float*)d_in[0];
  const float* w_experts = (const float*)d_in[1];
  const float* bn_gamma  = (const float*)d_in[2];
  const float* bn_beta   = (const float*)d_in[3];
  const float* bn_mean   = (const float*)d_in[4];
  const float* bn_var    = (const float*)d_in[5];
  const float* scales    = (const float*)d_in[6];
  const float* w_out     = (const float*)d_in[7];
  const float* out_gamma = (const float*)d_in[8];
  const float* out_beta  = (const float*)d_in[9];
  const float* out_mean  = (const float*)d_in[10];
  const float* out_var   = (const float*)d_in[11];
  float* out = (float*)d_out;

  char* ws = (char*)d_ws;
  float* eff_kernel = (float*)(ws);             // 9216 B
  float* eff_bias   = (float*)(ws + 9216);      // 1 KiB
  __bf16* w_eff     = (__bf16*)(ws + 10240);    // 128 KiB
  float* bias2      = (float*)(ws + 141312);    // 1 KiB

  hipLaunchKernelGGL(prep_kernel, dim3(257), dim3(256), 0, stream,
                     w_experts, bn_gamma, bn_beta, bn_mean, bn_var, scales,
                     w_out, out_gamma, out_beta, out_mean, out_var,
                     eff_kernel, eff_bias, w_eff, bias2);
  hipLaunchKernelGGL(fused_kernel, dim3(512), dim3(256), 0, stream,
                     x, eff_kernel, eff_bias, w_eff, bias2, out);
}